// Round 1
// baseline (34.975 us; speedup 1.0000x reference)
//
#include <hip/hip_runtime.h>

// Dilated attention, collapsed form.
// q,k,v: [B=4, D=256, N=8192] f32 (n contiguous). out: [B, N, D] f32.
// HEAD_DIM=32, heads H=8, kernel offsets {-2,0,+2}, 6 zero-pad slots in softmax.

constexpr int Bn = 4;
constexpr int Dd = 256;
constexpr int Nn = 8192;
constexpr int HD = 32;
constexpr int Hh = Dd / HD;          // 8
constexpr float SCALE = 0.17677669529663687f;  // 32^-0.5

__global__ __launch_bounds__(256) void dilate_attn_kernel(
    const float* __restrict__ q,
    const float* __restrict__ k,
    const float* __restrict__ v,
    float* __restrict__ out)
{
    const int gid = blockIdx.x * blockDim.x + threadIdx.x;   // B*H*N threads
    const int n  = gid & (Nn - 1);          // consecutive lanes -> consecutive n
    const int bh = gid >> 13;               // N = 8192 = 2^13
    const int h  = bh & (Hh - 1);
    const int b  = bh >> 3;

    const long base = ((long)b * Dd + (long)h * HD) * Nn + n;
    const float* qb = q + base;
    const float* kb = k + base;
    const float* vb = v + base;

    const bool left  = (n >= 2);
    const bool right = (n < Nn - 2);

    float s0 = 0.f, s1 = 0.f, s2 = 0.f;
    float qreg[HD];

    #pragma unroll
    for (int c = 0; c < HD; ++c) {
        const float qc = qb[(long)c * Nn];
        qreg[c] = qc;
        const float k1 = kb[(long)c * Nn];
        const float k0 = left  ? kb[(long)c * Nn - 2] : 0.f;
        const float k2 = right ? kb[(long)c * Nn + 2] : 0.f;
        s0 = fmaf(qc, k0, s0);
        s1 = fmaf(qc, k1, s1);
        s2 = fmaf(qc, k2, s2);
    }
    s0 *= SCALE; s1 *= SCALE; s2 *= SCALE;

    // softmax over [s0,s1,s2] plus six exact-zero logits (padding slots)
    const float m  = fmaxf(fmaxf(s0, s1), fmaxf(s2, 0.f));
    const float e0 = __expf(s0 - m);
    const float e1 = __expf(s1 - m);
    const float e2 = __expf(s2 - m);
    const float ez = __expf(-m);
    const float inv = 1.f / (e0 + e1 + e2 + 6.f * ez);
    const float p0 = e0 * inv, p1 = e1 * inv, p2 = e2 * inv;

    float o[HD];
    #pragma unroll
    for (int c = 0; c < HD; ++c) {
        const float v1 = vb[(long)c * Nn];
        const float v0 = left  ? vb[(long)c * Nn - 2] : 0.f;
        const float v2 = right ? vb[(long)c * Nn + 2] : 0.f;
        o[c] = fmaf(p0, v0, fmaf(p1, v1, p2 * v2));
    }

    // out[b][n][h*32 + c], c contiguous: 8x float4 per thread (128 B contiguous)
    float* ob = out + ((long)b * Nn + n) * Dd + (long)h * HD;
    #pragma unroll
    for (int c = 0; c < HD; c += 4) {
        float4 t;
        t.x = o[c]; t.y = o[c + 1]; t.z = o[c + 2]; t.w = o[c + 3];
        *reinterpret_cast<float4*>(ob + c) = t;
    }
}

extern "C" void kernel_launch(void* const* d_in, const int* in_sizes, int n_in,
                              void* d_out, int out_size, void* d_ws, size_t ws_size,
                              hipStream_t stream)
{
    const float* q = (const float*)d_in[0];
    const float* k = (const float*)d_in[1];
    const float* v = (const float*)d_in[2];
    float* out = (float*)d_out;

    const int total = Bn * Hh * Nn;          // 262144 threads
    dilate_attn_kernel<<<total / 256, 256, 0, stream>>>(q, k, v, out);
}